// Round 7
// baseline (362.658 us; speedup 1.0000x reference)
//
#include <hip/hip_runtime.h>
#include <hip/hip_bf16.h>
#include <math.h>

#define D_MODEL 1024
#define NUM_HEADS 16
#define D_K 64
#define BATCH 16
#define SEQ 512

typedef __attribute__((ext_vector_type(8))) short short8;
typedef __attribute__((ext_vector_type(4))) float floatx4;

__device__ inline unsigned short f2bf(float f) {
  __hip_bfloat16 h = __float2bfloat16(f);
  return *reinterpret_cast<unsigned short*>(&h);
}
__device__ inline float bf2f(unsigned short us) {
  unsigned u = ((unsigned)us) << 16;
  return __uint_as_float(u);
}

typedef const __attribute__((address_space(1))) unsigned int glb_u32;
typedef __attribute__((address_space(3))) unsigned int lds_u32;

__device__ inline void load16_to_lds(const void* g, void* l) {
  __builtin_amdgcn_global_load_lds((glb_u32*)(uintptr_t)g,
                                   (lds_u32*)(unsigned int)(uintptr_t)l, 16, 0,
                                   0);
}

// ---------------------------------------------------------------------------
// Fused fp32 -> bf16 convert for all 7 tensors (one dispatch). (R5 verified)
// ---------------------------------------------------------------------------
__global__ __launch_bounds__(256) void conv_all(
    const float* __restrict__ q, const float* __restrict__ k,
    const float* __restrict__ v, const float* __restrict__ w0,
    const float* __restrict__ w1, const float* __restrict__ w2,
    const float* __restrict__ w3, unsigned short* __restrict__ xq,
    unsigned short* __restrict__ xk, unsigned short* __restrict__ xv,
    unsigned short* __restrict__ d0, unsigned short* __restrict__ d1,
    unsigned short* __restrict__ d2, unsigned short* __restrict__ d3) {
  const size_t MG = 1048576, WG = 131072;
  const size_t g = (size_t)blockIdx.x * 256 + threadIdx.x;
  const float* src;
  unsigned short* dst;
  size_t idx;
  if (g < 3 * MG) {
    const int r = (int)(g >> 20);
    idx = g & (MG - 1);
    src = (r == 0) ? q : (r == 1) ? k : v;
    dst = (r == 0) ? xq : (r == 1) ? xk : xv;
  } else {
    const size_t gw = g - 3 * MG;
    const int r = (int)(gw >> 17);
    idx = gw & (WG - 1);
    src = (r == 0) ? w0 : (r == 1) ? w1 : (r == 2) ? w2 : w3;
    dst = (r == 0) ? d0 : (r == 1) ? d1 : (r == 2) ? d2 : d3;
  }
  const float4 a = ((const float4*)src)[2 * idx];
  const float4 b = ((const float4*)src)[2 * idx + 1];
  short8 o;
  o[0] = f2bf(a.x); o[1] = f2bf(a.y); o[2] = f2bf(a.z); o[3] = f2bf(a.w);
  o[4] = f2bf(b.x); o[5] = f2bf(b.y); o[6] = f2bf(b.z); o[7] = f2bf(b.w);
  ((short8*)dst)[idx] = o;
}

// ---------------------------------------------------------------------------
// Fused QKV GEMM: XCD swizzle (T1) + dbuf A in LDS + B READ DIRECT FROM L2.
// B (weights, 2MB/z) is L2-resident; reading fragments straight from global
// frees 32KB LDS -> 4-5 blocks/CU (TLP hides the barrier drain + L2 latency,
// robust to compiler scheduling — lesson of R3/R6).
// ---------------------------------------------------------------------------
__global__ __launch_bounds__(256, 4) void qkv_gemm(
    const unsigned short* __restrict__ Xall,  // xq | xk | xv (ME each)
    const unsigned short* __restrict__ Wall,  // wqb | wkb | wvb (WE each)
    const float* __restrict__ bq, const float* __restrict__ bk,
    const float* __restrict__ bv,
    unsigned short* __restrict__ QKout,  // Qb | Kb (ME each)
    unsigned short* __restrict__ Vt) {
  constexpr int K = 1024;
  const size_t ME = (size_t)BATCH * SEQ * D_MODEL;
  const size_t WE = (size_t)D_MODEL * D_MODEL;

  // ---- XCD-aware swizzle: grid (8,64,3) = 1536 blocks, 1536 % 8 == 0 ----
  const int f = blockIdx.x + (blockIdx.y << 3) + (blockIdx.z << 9);
  const int virt = ((f & 7) * 192) + (f >> 3);
  const int xi = virt & 7;     // N tile 0..7
  const int rest = virt >> 3;  // 0..191
  const int yi = rest & 63;    // M tile 0..63
  const int z = rest >> 6;     // 0..2 {Q,K,V}

  const unsigned short* A = Xall + (size_t)z * ME;
  const unsigned short* Bw = Wall + (size_t)z * WE;
  const float* bias = (z == 0) ? bq : (z == 1) ? bk : bv;

  __shared__ __align__(16) unsigned short sA[2][128 * 64];
  const int tid = threadIdx.x;
  const int w = tid >> 6, lane = tid & 63;
  const int quad = lane >> 4, lq = lane & 15;
  const int wm = w >> 1, wn = w & 1;
  const int m0 = yi << 7, n0 = xi << 7;

  const int lrow8 = lane >> 3;
  const int sg = lane & 7;

  floatx4 acc[4][4];
#pragma unroll
  for (int i = 0; i < 4; ++i)
#pragma unroll
    for (int j = 0; j < 4; ++j) acc[i][j] = {0.f, 0.f, 0.f, 0.f};

  // per-thread B row base (row fixed by ni only; hoisted)
  const unsigned short* browp[4];
#pragma unroll
  for (int ni = 0; ni < 4; ++ni)
    browp[ni] = Bw + (size_t)(n0 + (wn << 6) + (ni << 4) + lq) * K;

  auto stageA = [&](int buf, int kt) {
#pragma unroll
    for (int i = 0; i < 4; ++i) {
      const int row = (i << 5) + (w << 3) + lrow8;
      const int g = sg ^ (row & 7);
      const unsigned short* gA = A + (size_t)(m0 + row) * K + kt + (g << 3);
      load16_to_lds(gA, &sA[buf][((i << 5) + (w << 3)) * 64]);
    }
  };

  stageA(0, 0);
  __syncthreads();
  int cur = 0;
  for (int kt = 0; kt < K; kt += 64) {
    if (kt + 64 < K) stageA(cur ^ 1, kt + 64);
#pragma unroll
    for (int s = 0; s < 2; ++s) {
      short8 aF[4], bF[4];
#pragma unroll
      for (int ni = 0; ni < 4; ++ni)
        bF[ni] = *(const short8*)(browp[ni] + kt + (s << 5) + (quad << 3));
#pragma unroll
      for (int mi = 0; mi < 4; ++mi) {
        const int row = (wm << 6) + (mi << 4) + lq;
        const int g = ((s << 2) + quad) ^ (row & 7);
        aF[mi] = *(const short8*)&sA[cur][row * 64 + (g << 3)];
      }
#pragma unroll
      for (int mi = 0; mi < 4; ++mi)
#pragma unroll
        for (int ni = 0; ni < 4; ++ni)
          acc[mi][ni] = __builtin_amdgcn_mfma_f32_16x16x32_bf16(
              aF[mi], bF[ni], acc[mi][ni], 0, 0, 0);
    }
    __syncthreads();
    cur ^= 1;
  }

#pragma unroll
  for (int ni = 0; ni < 4; ++ni) {
    const int n = n0 + (wn << 6) + (ni << 4) + lq;
    const float bn = bias[n];
    const int hh = n >> 6, dk = n & 63;
#pragma unroll
    for (int mi = 0; mi < 4; ++mi) {
      const int mb = m0 + (wm << 6) + (mi << 4) + (quad << 2);
      const int bb = mb >> 9, ss = mb & 511;
      if (z == 2) {
        ushort4 pk;
        pk.x = f2bf(acc[mi][ni][0] + bn);
        pk.y = f2bf(acc[mi][ni][1] + bn);
        pk.z = f2bf(acc[mi][ni][2] + bn);
        pk.w = f2bf(acc[mi][ni][3] + bn);
        *(ushort4*)&Vt[((size_t)(bb * NUM_HEADS + hh) * D_K + dk) * SEQ + ss] =
            pk;
      } else {
        unsigned short* dst = QKout + (size_t)z * ME;
#pragma unroll
        for (int r = 0; r < 4; ++r)
          dst[((size_t)(bb * NUM_HEADS + hh) * SEQ + ss + r) * D_K + dk] =
              f2bf(acc[mi][ni][r] + bn);
      }
    }
  }
}

// ---------------------------------------------------------------------------
// Output projection GEMM: XCD swizzle + double-buffered prefetch (R5 verified).
// ---------------------------------------------------------------------------
__global__ __launch_bounds__(256) void out_gemm(
    const unsigned short* __restrict__ A, const unsigned short* __restrict__ Bw,
    const float* __restrict__ bias, float* __restrict__ Cout) {
  constexpr int K = 1024;
  __shared__ __align__(16) unsigned short sA[2][128 * 64];
  __shared__ __align__(16) unsigned short sB[2][128 * 64];
  const int tid = threadIdx.x;
  const int w = tid >> 6, lane = tid & 63;
  const int quad = lane >> 4, lq = lane & 15;
  const int wm = w >> 1, wn = w & 1;

  // ---- XCD-aware swizzle: grid (8,64) = 512 blocks, 512 % 8 == 0 ----
  const int f = blockIdx.x + (blockIdx.y << 3);
  const int virt = ((f & 7) << 6) + (f >> 3);
  const int m0 = (virt >> 3) << 7, n0 = (virt & 7) << 7;

  const int lrow8 = lane >> 3;
  const int sg = lane & 7;

  floatx4 acc[4][4];
#pragma unroll
  for (int i = 0; i < 4; ++i)
#pragma unroll
    for (int j = 0; j < 4; ++j) acc[i][j] = {0.f, 0.f, 0.f, 0.f};

  auto stage = [&](int buf, int kt) {
#pragma unroll
    for (int i = 0; i < 4; ++i) {
      const int row = (i << 5) + (w << 3) + lrow8;
      const int g = sg ^ (row & 7);
      const unsigned short* gA = A + (size_t)(m0 + row) * K + kt + (g << 3);
      const unsigned short* gB = Bw + (size_t)(n0 + row) * K + kt + (g << 3);
      load16_to_lds(gA, &sA[buf][((i << 5) + (w << 3)) * 64]);
      load16_to_lds(gB, &sB[buf][((i << 5) + (w << 3)) * 64]);
    }
  };

  stage(0, 0);
  __syncthreads();
  int cur = 0;
  for (int kt = 0; kt < K; kt += 64) {
    if (kt + 64 < K) stage(cur ^ 1, kt + 64);
#pragma unroll
    for (int s = 0; s < 2; ++s) {
      short8 aF[4], bF[4];
#pragma unroll
      for (int mi = 0; mi < 4; ++mi) {
        const int row = (wm << 6) + (mi << 4) + lq;
        const int g = ((s << 2) + quad) ^ (row & 7);
        aF[mi] = *(const short8*)&sA[cur][row * 64 + (g << 3)];
      }
#pragma unroll
      for (int ni = 0; ni < 4; ++ni) {
        const int row = (wn << 6) + (ni << 4) + lq;
        const int g = ((s << 2) + quad) ^ (row & 7);
        bF[ni] = *(const short8*)&sB[cur][row * 64 + (g << 3)];
      }
#pragma unroll
      for (int mi = 0; mi < 4; ++mi)
#pragma unroll
        for (int ni = 0; ni < 4; ++ni)
          acc[mi][ni] = __builtin_amdgcn_mfma_f32_16x16x32_bf16(
              aF[mi], bF[ni], acc[mi][ni], 0, 0, 0);
    }
    __syncthreads();
    cur ^= 1;
  }

#pragma unroll
  for (int ni = 0; ni < 4; ++ni) {
    const int n = n0 + (wn << 6) + (ni << 4) + lq;
    const float bn = bias[n];
#pragma unroll
    for (int mi = 0; mi < 4; ++mi) {
      const int mb = m0 + (wm << 6) + (mi << 4) + (quad << 2);
#pragma unroll
      for (int r = 0; r < 4; ++r)
        Cout[(size_t)(mb + r) * 1024 + n] = acc[mi][ni][r] + bn;
    }
  }
}

// ---------------------------------------------------------------------------
// Fixed-max MFMA attention, v4.1: K/V resident in LDS (R5 verified) +
// causal-mask hoist: only the diagonal chunk (c == nc-1) needs col<=row;
// off-diagonal chunks drop 16 cmp+cndmask per lane (wave-uniform branch).
// ---------------------------------------------------------------------------
__global__ __launch_bounds__(512) void attn_mfma(
    const unsigned short* __restrict__ Qb,  // [B,H,S,64] bf16
    const unsigned short* __restrict__ Kb,  // [B,H,S,64] bf16
    const unsigned short* __restrict__ Vt,  // [B,H,64,S] bf16
    const float* __restrict__ rb,           // [H,512,512] fp32
    unsigned short* __restrict__ ctxb,      // [B,S,1024] bf16
    unsigned short* __restrict__ Pg,        // [B,H,S,S] bf16, unnorm exp(v)
    float* __restrict__ flWS) {             // [B,H,S]  1/(16 l)
  const int b = blockIdx.x;
  const int h = blockIdx.y;
  const int tid = threadIdx.x;
  const int w = tid >> 6, lane = tid & 63;
  const int quad = lane >> 4, lq = lane & 15;

  __shared__ __align__(16) unsigned short sK[512 * 64];   // 64 KB, rows 128B
  __shared__ __align__(16) unsigned short sV[64 * 512];   // 64 KB, rows 1KB
  __shared__ __align__(16) unsigned short sPt[8][16][72]; // 18 KB

  const size_t bh = (size_t)b * NUM_HEADS + h;
  const unsigned short* Qh = Qb + bh * SEQ * D_K;
  const unsigned short* Kh = Kb + bh * SEQ * D_K;
  const unsigned short* Vh = Vt + bh * D_K * SEQ;
  const float* rbh = rb + (size_t)h * SEQ * SEQ;

  // ---- stage K,V -> LDS; source pre-swizzled so swizzled reads are linear
#pragma unroll
  for (int it = 0; it < 8; ++it) {
    const int L = (it << 13) + (tid << 4);  // byte offset, 8KB/iter
    {
      const int rk = L >> 7, ck = (L >> 4) & 7;
      load16_to_lds(
          (const unsigned char*)Kh + (L & ~127) + ((ck ^ (rk & 7)) << 4),
          (unsigned char*)sK + L);
    }
    {
      const int rv = L >> 10, cv = (L >> 4) & 63;
      load16_to_lds(
          (const unsigned char*)Vh + (L & ~1023) + ((cv ^ (rv & 7)) << 4),
          (unsigned char*)sV + L);
    }
  }
  __syncthreads();

#pragma unroll 1
  for (int si = 0; si < 4; ++si) {
    const int st = (si == 0) ? w : (si == 1) ? (15 - w)
                 : (si == 2) ? (16 + w) : (31 - w);
    const int qs = st << 4;
    const int nc = (st >> 2) + 1;

    short8 aQ0, aQ1;
    {
      const unsigned short* qrow = Qh + (size_t)(qs + lq) * D_K + (quad << 3);
      aQ0 = *(const short8*)(qrow);
      aQ1 = *(const short8*)(qrow + 32);
    }

    float lsum[4] = {0.f, 0.f, 0.f, 0.f};
    floatx4 O[4] = {{0.f, 0.f, 0.f, 0.f},
                    {0.f, 0.f, 0.f, 0.f},
                    {0.f, 0.f, 0.f, 0.f},
                    {0.f, 0.f, 0.f, 0.f}};

    const float* rbbase = rbh + (size_t)(qs + (quad << 2)) * SEQ + lq;
    float rbv[16];
#pragma unroll
    for (int nt = 0; nt < 4; ++nt)
#pragma unroll
      for (int r = 0; r < 4; ++r)
        rbv[nt * 4 + r] = rbbase[(size_t)r * SEQ + (nt << 4)];

    for (int c = 0; c < nc; ++c) {
      const int t0 = c << 6;
      const bool diag = (c == nc - 1);
      float rbn[16];
      if (c + 1 < nc) {
        const float* rn = rbbase + t0 + 64;
#pragma unroll
        for (int nt = 0; nt < 4; ++nt)
#pragma unroll
          for (int r = 0; r < 4; ++r)
            rbn[nt * 4 + r] = rn[(size_t)r * SEQ + (nt << 4)];
      }

#pragma unroll
      for (int nt = 0; nt < 4; ++nt) {
        const int kr = t0 + (nt << 4) + lq;
        const unsigned char* kbase = (const unsigned char*)sK + (kr << 7);
        short8 bK0 = *(const short8*)(kbase + ((quad ^ (kr & 7)) << 4));
        short8 bK1 = *(const short8*)(kbase + (((quad + 4) ^ (kr & 7)) << 4));
        floatx4 s = {0.f, 0.f, 0.f, 0.f};
        s = __builtin_amdgcn_mfma_f32_16x16x32_bf16(aQ0, bK0, s, 0, 0, 0);
        s = __builtin_amdgcn_mfma_f32_16x16x32_bf16(aQ1, bK1, s, 0, 0, 0);
        if (diag) {
          const int col = t0 + (nt << 4) + lq;
#pragma unroll
          for (int r = 0; r < 4; ++r) {
            const int row = qs + (quad << 2) + r;
            float p = 0.f;
            if (col <= row) p = __expf(s[r] * 0.125f + rbv[nt * 4 + r]);
            lsum[r] += p;
            sPt[w][(quad << 2) + r][(nt << 4) + lq] = f2bf(p);
          }
        } else {
#pragma unroll
          for (int r = 0; r < 4; ++r) {
            const float p = __expf(s[r] * 0.125f + rbv[nt * 4 + r]);
            lsum[r] += p;
            sPt[w][(quad << 2) + r][(nt << 4) + lq] = f2bf(p);
          }
        }
      }

      short8 bV0[4], bV1[4];
#pragma unroll
      for (int nt = 0; nt < 4; ++nt) {
        const int vr = (nt << 4) + lq;
        const unsigned char* vbase = (const unsigned char*)sV + (vr << 10);
        const int cc = (t0 >> 3) + quad;
        bV0[nt] = *(const short8*)(vbase + ((cc ^ (vr & 7)) << 4));
        bV1[nt] = *(const short8*)(vbase + (((cc + 4) ^ (vr & 7)) << 4));
      }

      short8 aP0 = *(const short8*)&sPt[w][lq][quad << 3];
      short8 aP1 = *(const short8*)&sPt[w][lq][32 + (quad << 3)];

      {
        unsigned short* pgrow =
            Pg + (bh * SEQ + (qs + lq)) * SEQ + t0 + (quad << 3);
        *(short8*)pgrow = aP0;
        *(short8*)(pgrow + 32) = aP1;
      }

#pragma unroll
      for (int nt = 0; nt < 4; ++nt) {
        O[nt] = __builtin_amdgcn_mfma_f32_16x16x32_bf16(aP0, bV0[nt], O[nt], 0,
                                                        0, 0);
        O[nt] = __builtin_amdgcn_mfma_f32_16x16x32_bf16(aP1, bV1[nt], O[nt], 0,
                                                        0, 0);
      }

      if (c + 1 < nc) {
#pragma unroll
        for (int i = 0; i < 16; ++i) rbv[i] = rbn[i];
      }
    }

#pragma unroll
    for (int off = 1; off < 16; off <<= 1)
#pragma unroll
      for (int r = 0; r < 4; ++r) lsum[r] += __shfl_xor(lsum[r], off);
    float invl[4];
#pragma unroll
    for (int r = 0; r < 4; ++r) invl[r] = 1.f / lsum[r];
    if (lq == 0) {
#pragma unroll
      for (int r = 0; r < 4; ++r)
        flWS[bh * SEQ + qs + (quad << 2) + r] = invl[r] * 0.0625f;
    }
#pragma unroll
    for (int nt = 0; nt < 4; ++nt)
#pragma unroll
      for (int r = 0; r < 4; ++r) {
        const int row = qs + (quad << 2) + r;
        ctxb[((size_t)b * SEQ + row) * D_MODEL + h * D_K + (nt << 4) + lq] =
            f2bf(O[nt][r] * invl[r]);
      }
  }
}

// ---------------------------------------------------------------------------
// Head-mean reduce (unchanged).
// ---------------------------------------------------------------------------
__global__ __launch_bounds__(256) void attn_reduce(
    const unsigned short* __restrict__ Pg, const float* __restrict__ flWS,
    float* __restrict__ attn_mean) {
  const int b = blockIdx.x, rt = blockIdx.y, cs = blockIdx.z;
#pragma unroll
  for (int k = 0; k < 4; ++k) {
    const int slot = threadIdx.x + (k << 8);
    const int row = (rt << 6) + (slot >> 4);
    const int col0 = (cs << 7) + ((slot & 15) << 3);
    float acc[8] = {0.f, 0.f, 0.f, 0.f, 0.f, 0.f, 0.f, 0.f};
    if (col0 <= row) {
      for (int h = 0; h < NUM_HEADS; ++h) {
        const size_t base = (((size_t)b * NUM_HEADS + h) << 9) + row;
        const float f = flWS[base];
        const uint4 pk = *(const uint4*)&Pg[(base << 9) + col0];
        acc[0] += bf2f((unsigned short)(pk.x & 0xffff)) * f;
        acc[1] += bf2f((unsigned short)(pk.x >> 16)) * f;
        acc[2] += bf2f((unsigned short)(pk.y & 0xffff)) * f;
        acc[3] += bf2f((unsigned short)(pk.y >> 16)) * f;
        acc[4] += bf2f((unsigned short)(pk.z & 0xffff)) * f;
        acc[5] += bf2f((unsigned short)(pk.z >> 16)) * f;
        acc[6] += bf2f((unsigned short)(pk.w & 0xffff)) * f;
        acc[7] += bf2f((unsigned short)(pk.w >> 16)) * f;
      }
    }
    float4 o0, o1;
    o0.x = (col0 + 0 <= row) ? acc[0] : 0.f;
    o0.y = (col0 + 1 <= row) ? acc[1] : 0.f;
    o0.z = (col0 + 2 <= row) ? acc[2] : 0.f;
    o0.w = (col0 + 3 <= row) ? acc[3] : 0.f;
    o1.x = (col0 + 4 <= row) ? acc[4] : 0.f;
    o1.y = (col0 + 5 <= row) ? acc[5] : 0.f;
    o1.z = (col0 + 6 <= row) ? acc[6] : 0.f;
    o1.w = (col0 + 7 <= row) ? acc[7] : 0.f;
    float* dst = attn_mean + (((size_t)b << 9) + row) * SEQ + col0;
    *(float4*)dst = o0;
    *(float4*)(dst + 4) = o1;
  }
}

// ---------------------------------------------------------------------------
extern "C" void kernel_launch(void* const* d_in, const int* in_sizes, int n_in,
                              void* d_out, int out_size, void* d_ws,
                              size_t ws_size, hipStream_t stream) {
  const float* query = (const float*)d_in[0];
  const float* key_ = (const float*)d_in[1];
  const float* value = (const float*)d_in[2];
  const float* wq_w = (const float*)d_in[3];
  const float* wq_b = (const float*)d_in[4];
  const float* wk_w = (const float*)d_in[5];
  const float* wk_b = (const float*)d_in[6];
  const float* wv_w = (const float*)d_in[7];
  const float* wv_b = (const float*)d_in[8];
  const float* wo_w = (const float*)d_in[9];
  const float* wo_b = (const float*)d_in[10];
  const float* rel_bias = (const float*)d_in[11];

  float* out = (float*)d_out;                              // [B,S,1024]
  float* attn_mean = out + (size_t)BATCH * SEQ * D_MODEL;  // [B,S,512]

  const size_t ME = (size_t)BATCH * SEQ * D_MODEL;    // 8.4M elems
  const size_t WE = (size_t)D_MODEL * D_MODEL;        // 1M elems
  const size_t RE = (size_t)BATCH * NUM_HEADS * SEQ;  // 131072 rows

  unsigned short* Qb = (unsigned short*)d_ws;  // Qb | Kb contiguous
  unsigned short* Kb = Qb + ME;
  unsigned short* Vt = Kb + ME;
  unsigned short* ctxb = Vt + ME;
  unsigned short* wob = ctxb + ME;                    // 2 MB
  float* flWS = (float*)(wob + WE);                   // 0.5 MB
  unsigned short* Pg = (unsigned short*)(flWS + RE);  // 134 MB
  // transient buffers alias the Pg region (dead before attn writes Pg):
  unsigned short* xq = Pg;  // xq | xk | xv contiguous (ME each)
  unsigned short* xk = xq + ME;
  unsigned short* xv = xk + ME;
  unsigned short* wqb = xv + ME;  // wqb | wkb | wvb contiguous (WE each)
  unsigned short* wkb = wqb + WE;
  unsigned short* wvb = wkb + WE;

  conv_all<<<14336, 256, 0, stream>>>(query, key_, value, wq_w, wk_w, wv_w,
                                      wo_w, xq, xk, xv, wqb, wkb, wvb, wob);

  dim3 qkvg(8, 64, 3);  // N/128 x M/128 x {Q,K,V} (swizzled in-kernel)
  qkv_gemm<<<qkvg, 256, 0, stream>>>(xq, wqb, wq_b, wk_b, wv_b, Qb, Vt);

  dim3 agrid(BATCH, NUM_HEADS);  // one block per (b,h), K/V in LDS
  attn_mfma<<<agrid, 512, 0, stream>>>(Qb, Kb, Vt, rel_bias, ctxb, Pg, flWS);

  dim3 rgrid(BATCH, 8, 4);
  attn_reduce<<<rgrid, 256, 0, stream>>>(Pg, flWS, attn_mean);

  dim3 gblk(8, 64);
  out_gemm<<<gblk, 256, 0, stream>>>(ctxb, wob, wo_b, out);
}

// Round 8
// 308.715 us; speedup vs baseline: 1.1747x; 1.1747x over previous
//
#include <hip/hip_runtime.h>
#include <hip/hip_bf16.h>
#include <math.h>

#define D_MODEL 1024
#define NUM_HEADS 16
#define D_K 64
#define BATCH 16
#define SEQ 512

typedef __attribute__((ext_vector_type(8))) short short8;
typedef __attribute__((ext_vector_type(4))) float floatx4;

__device__ inline unsigned short f2bf(float f) {
  __hip_bfloat16 h = __float2bfloat16(f);
  return *reinterpret_cast<unsigned short*>(&h);
}
__device__ inline float bf2f(unsigned short us) {
  unsigned u = ((unsigned)us) << 16;
  return __uint_as_float(u);
}

typedef const __attribute__((address_space(1))) unsigned int glb_u32;
typedef __attribute__((address_space(3))) unsigned int lds_u32;

__device__ inline void load16_to_lds(const void* g, void* l) {
  __builtin_amdgcn_global_load_lds((glb_u32*)(uintptr_t)g,
                                   (lds_u32*)(unsigned int)(uintptr_t)l, 16, 0,
                                   0);
}

// ---------------------------------------------------------------------------
// Fused fp32 -> bf16 convert for all 7 tensors (one dispatch). (R5 verified)
// ---------------------------------------------------------------------------
__global__ __launch_bounds__(256) void conv_all(
    const float* __restrict__ q, const float* __restrict__ k,
    const float* __restrict__ v, const float* __restrict__ w0,
    const float* __restrict__ w1, const float* __restrict__ w2,
    const float* __restrict__ w3, unsigned short* __restrict__ xq,
    unsigned short* __restrict__ xk, unsigned short* __restrict__ xv,
    unsigned short* __restrict__ d0, unsigned short* __restrict__ d1,
    unsigned short* __restrict__ d2, unsigned short* __restrict__ d3) {
  const size_t MG = 1048576, WG = 131072;
  const size_t g = (size_t)blockIdx.x * 256 + threadIdx.x;
  const float* src;
  unsigned short* dst;
  size_t idx;
  if (g < 3 * MG) {
    const int r = (int)(g >> 20);
    idx = g & (MG - 1);
    src = (r == 0) ? q : (r == 1) ? k : v;
    dst = (r == 0) ? xq : (r == 1) ? xk : xv;
  } else {
    const size_t gw = g - 3 * MG;
    const int r = (int)(gw >> 17);
    idx = gw & (WG - 1);
    src = (r == 0) ? w0 : (r == 1) ? w1 : (r == 2) ? w2 : w3;
    dst = (r == 0) ? d0 : (r == 1) ? d1 : (r == 2) ? d2 : d3;
  }
  const float4 a = ((const float4*)src)[2 * idx];
  const float4 b = ((const float4*)src)[2 * idx + 1];
  short8 o;
  o[0] = f2bf(a.x); o[1] = f2bf(a.y); o[2] = f2bf(a.z); o[3] = f2bf(a.w);
  o[4] = f2bf(b.x); o[5] = f2bf(b.y); o[6] = f2bf(b.z); o[7] = f2bf(b.w);
  ((short8*)dst)[idx] = o;
}

// ---------------------------------------------------------------------------
// Fused QKV GEMM: XCD swizzle (T1) + double-buffered LDS prefetch (T3-min).
// R5-verified: 63 µs, MfmaUtil 35%. Both A and B staged via global_load_lds —
// R6 (reg-staged A) and R7 (L2-direct B) both regressed ~2x; this is the
// 2-barrier structure's measured optimum.
// ---------------------------------------------------------------------------
__global__ __launch_bounds__(256) void qkv_gemm(
    const unsigned short* __restrict__ Xall,  // xq | xk | xv (ME each)
    const unsigned short* __restrict__ Wall,  // wqb | wkb | wvb (WE each)
    const float* __restrict__ bq, const float* __restrict__ bk,
    const float* __restrict__ bv,
    unsigned short* __restrict__ QKout,  // Qb | Kb (ME each)
    unsigned short* __restrict__ Vt) {
  constexpr int K = 1024;
  const size_t ME = (size_t)BATCH * SEQ * D_MODEL;
  const size_t WE = (size_t)D_MODEL * D_MODEL;

  // ---- XCD-aware swizzle: grid (8,64,3) = 1536 blocks, 1536 % 8 == 0 ----
  const int f = blockIdx.x + (blockIdx.y << 3) + (blockIdx.z << 9);
  const int virt = ((f & 7) * 192) + (f >> 3);
  const int xi = virt & 7;     // N tile 0..7
  const int rest = virt >> 3;  // 0..191
  const int yi = rest & 63;    // M tile 0..63
  const int z = rest >> 6;     // 0..2 {Q,K,V}

  const unsigned short* A = Xall + (size_t)z * ME;
  const unsigned short* Bw = Wall + (size_t)z * WE;
  const float* bias = (z == 0) ? bq : (z == 1) ? bk : bv;

  __shared__ __align__(16) unsigned short sA[2][128 * 64];
  __shared__ __align__(16) unsigned short sB[2][128 * 64];
  const int tid = threadIdx.x;
  const int w = tid >> 6, lane = tid & 63;
  const int quad = lane >> 4, lq = lane & 15;
  const int wm = w >> 1, wn = w & 1;
  const int m0 = yi << 7, n0 = xi << 7;

  const int lrow8 = lane >> 3;
  const int sg = lane & 7;

  floatx4 acc[4][4];
#pragma unroll
  for (int i = 0; i < 4; ++i)
#pragma unroll
    for (int j = 0; j < 4; ++j) acc[i][j] = {0.f, 0.f, 0.f, 0.f};

  // stage K-tile kt into LDS buffer buf
  auto stage = [&](int buf, int kt) {
#pragma unroll
    for (int i = 0; i < 4; ++i) {
      const int row = (i << 5) + (w << 3) + lrow8;
      const int g = sg ^ (row & 7);
      const unsigned short* gA = A + (size_t)(m0 + row) * K + kt + (g << 3);
      const unsigned short* gB = Bw + (size_t)(n0 + row) * K + kt + (g << 3);
      load16_to_lds(gA, &sA[buf][((i << 5) + (w << 3)) * 64]);
      load16_to_lds(gB, &sB[buf][((i << 5) + (w << 3)) * 64]);
    }
  };

  stage(0, 0);
  __syncthreads();
  int cur = 0;
  for (int kt = 0; kt < K; kt += 64) {
    if (kt + 64 < K) stage(cur ^ 1, kt + 64);
#pragma unroll
    for (int s = 0; s < 2; ++s) {
      short8 aF[4], bF[4];
#pragma unroll
      for (int mi = 0; mi < 4; ++mi) {
        const int row = (wm << 6) + (mi << 4) + lq;
        const int g = ((s << 2) + quad) ^ (row & 7);
        aF[mi] = *(const short8*)&sA[cur][row * 64 + (g << 3)];
      }
#pragma unroll
      for (int ni = 0; ni < 4; ++ni) {
        const int row = (wn << 6) + (ni << 4) + lq;
        const int g = ((s << 2) + quad) ^ (row & 7);
        bF[ni] = *(const short8*)&sB[cur][row * 64 + (g << 3)];
      }
#pragma unroll
      for (int mi = 0; mi < 4; ++mi)
#pragma unroll
        for (int ni = 0; ni < 4; ++ni)
          acc[mi][ni] = __builtin_amdgcn_mfma_f32_16x16x32_bf16(
              aF[mi], bF[ni], acc[mi][ni], 0, 0, 0);
    }
    __syncthreads();
    cur ^= 1;
  }

#pragma unroll
  for (int ni = 0; ni < 4; ++ni) {
    const int n = n0 + (wn << 6) + (ni << 4) + lq;
    const float bn = bias[n];
    const int hh = n >> 6, dk = n & 63;
#pragma unroll
    for (int mi = 0; mi < 4; ++mi) {
      const int mb = m0 + (wm << 6) + (mi << 4) + (quad << 2);
      const int bb = mb >> 9, ss = mb & 511;
      if (z == 2) {
        ushort4 pk;
        pk.x = f2bf(acc[mi][ni][0] + bn);
        pk.y = f2bf(acc[mi][ni][1] + bn);
        pk.z = f2bf(acc[mi][ni][2] + bn);
        pk.w = f2bf(acc[mi][ni][3] + bn);
        *(ushort4*)&Vt[((size_t)(bb * NUM_HEADS + hh) * D_K + dk) * SEQ + ss] =
            pk;
      } else {
        unsigned short* dst = QKout + (size_t)z * ME;
#pragma unroll
        for (int r = 0; r < 4; ++r)
          dst[((size_t)(bb * NUM_HEADS + hh) * SEQ + ss + r) * D_K + dk] =
              f2bf(acc[mi][ni][r] + bn);
      }
    }
  }
}

// ---------------------------------------------------------------------------
// Output projection GEMM: XCD swizzle + double-buffered prefetch (R5 verified).
// ---------------------------------------------------------------------------
__global__ __launch_bounds__(256) void out_gemm(
    const unsigned short* __restrict__ A, const unsigned short* __restrict__ Bw,
    const float* __restrict__ bias, float* __restrict__ Cout) {
  constexpr int K = 1024;
  __shared__ __align__(16) unsigned short sA[2][128 * 64];
  __shared__ __align__(16) unsigned short sB[2][128 * 64];
  const int tid = threadIdx.x;
  const int w = tid >> 6, lane = tid & 63;
  const int quad = lane >> 4, lq = lane & 15;
  const int wm = w >> 1, wn = w & 1;

  // ---- XCD-aware swizzle: grid (8,64) = 512 blocks, 512 % 8 == 0 ----
  const int f = blockIdx.x + (blockIdx.y << 3);
  const int virt = ((f & 7) << 6) + (f >> 3);
  const int m0 = (virt >> 3) << 7, n0 = (virt & 7) << 7;

  const int lrow8 = lane >> 3;
  const int sg = lane & 7;

  floatx4 acc[4][4];
#pragma unroll
  for (int i = 0; i < 4; ++i)
#pragma unroll
    for (int j = 0; j < 4; ++j) acc[i][j] = {0.f, 0.f, 0.f, 0.f};

  auto stage = [&](int buf, int kt) {
#pragma unroll
    for (int i = 0; i < 4; ++i) {
      const int row = (i << 5) + (w << 3) + lrow8;
      const int g = sg ^ (row & 7);
      const unsigned short* gA = A + (size_t)(m0 + row) * K + kt + (g << 3);
      const unsigned short* gB = Bw + (size_t)(n0 + row) * K + kt + (g << 3);
      load16_to_lds(gA, &sA[buf][((i << 5) + (w << 3)) * 64]);
      load16_to_lds(gB, &sB[buf][((i << 5) + (w << 3)) * 64]);
    }
  };

  stage(0, 0);
  __syncthreads();
  int cur = 0;
  for (int kt = 0; kt < K; kt += 64) {
    if (kt + 64 < K) stage(cur ^ 1, kt + 64);
#pragma unroll
    for (int s = 0; s < 2; ++s) {
      short8 aF[4], bF[4];
#pragma unroll
      for (int mi = 0; mi < 4; ++mi) {
        const int row = (wm << 6) + (mi << 4) + lq;
        const int g = ((s << 2) + quad) ^ (row & 7);
        aF[mi] = *(const short8*)&sA[cur][row * 64 + (g << 3)];
      }
#pragma unroll
      for (int ni = 0; ni < 4; ++ni) {
        const int row = (wn << 6) + (ni << 4) + lq;
        const int g = ((s << 2) + quad) ^ (row & 7);
        bF[ni] = *(const short8*)&sB[cur][row * 64 + (g << 3)];
      }
#pragma unroll
      for (int mi = 0; mi < 4; ++mi)
#pragma unroll
        for (int ni = 0; ni < 4; ++ni)
          acc[mi][ni] = __builtin_amdgcn_mfma_f32_16x16x32_bf16(
              aF[mi], bF[ni], acc[mi][ni], 0, 0, 0);
    }
    __syncthreads();
    cur ^= 1;
  }

#pragma unroll
  for (int ni = 0; ni < 4; ++ni) {
    const int n = n0 + (wn << 6) + (ni << 4) + lq;
    const float bn = bias[n];
#pragma unroll
    for (int mi = 0; mi < 4; ++mi) {
      const int mb = m0 + (wm << 6) + (mi << 4) + (quad << 2);
#pragma unroll
      for (int r = 0; r < 4; ++r)
        Cout[(size_t)(mb + r) * 1024 + n] = acc[mi][ni][r] + bn;
    }
  }
}

// ---------------------------------------------------------------------------
// Fixed-max MFMA attention, v4.1: K/V resident in LDS (R4/R5 verified) +
// causal-mask hoist: only the diagonal chunk (c == nc-1) needs col<=row.
// ---------------------------------------------------------------------------
__global__ __launch_bounds__(512) void attn_mfma(
    const unsigned short* __restrict__ Qb,  // [B,H,S,64] bf16
    const unsigned short* __restrict__ Kb,  // [B,H,S,64] bf16
    const unsigned short* __restrict__ Vt,  // [B,H,64,S] bf16
    const float* __restrict__ rb,           // [H,512,512] fp32
    unsigned short* __restrict__ ctxb,      // [B,S,1024] bf16
    unsigned short* __restrict__ Pg,        // [B,H,S,S] bf16, unnorm exp(v)
    float* __restrict__ flWS) {             // [B,H,S]  1/(16 l)
  const int b = blockIdx.x;
  const int h = blockIdx.y;
  const int tid = threadIdx.x;
  const int w = tid >> 6, lane = tid & 63;
  const int quad = lane >> 4, lq = lane & 15;

  __shared__ __align__(16) unsigned short sK[512 * 64];   // 64 KB, rows 128B
  __shared__ __align__(16) unsigned short sV[64 * 512];   // 64 KB, rows 1KB
  __shared__ __align__(16) unsigned short sPt[8][16][72]; // 18 KB

  const size_t bh = (size_t)b * NUM_HEADS + h;
  const unsigned short* Qh = Qb + bh * SEQ * D_K;
  const unsigned short* Kh = Kb + bh * SEQ * D_K;
  const unsigned short* Vh = Vt + bh * D_K * SEQ;
  const float* rbh = rb + (size_t)h * SEQ * SEQ;

  // ---- stage K,V -> LDS; source pre-swizzled so swizzled reads are linear
#pragma unroll
  for (int it = 0; it < 8; ++it) {
    const int L = (it << 13) + (tid << 4);  // byte offset, 8KB/iter
    {
      const int rk = L >> 7, ck = (L >> 4) & 7;
      load16_to_lds(
          (const unsigned char*)Kh + (L & ~127) + ((ck ^ (rk & 7)) << 4),
          (unsigned char*)sK + L);
    }
    {
      const int rv = L >> 10, cv = (L >> 4) & 63;
      load16_to_lds(
          (const unsigned char*)Vh + (L & ~1023) + ((cv ^ (rv & 7)) << 4),
          (unsigned char*)sV + L);
    }
  }
  __syncthreads();

#pragma unroll 1
  for (int si = 0; si < 4; ++si) {
    const int st = (si == 0) ? w : (si == 1) ? (15 - w)
                 : (si == 2) ? (16 + w) : (31 - w);
    const int qs = st << 4;
    const int nc = (st >> 2) + 1;

    short8 aQ0, aQ1;
    {
      const unsigned short* qrow = Qh + (size_t)(qs + lq) * D_K + (quad << 3);
      aQ0 = *(const short8*)(qrow);
      aQ1 = *(const short8*)(qrow + 32);
    }

    float lsum[4] = {0.f, 0.f, 0.f, 0.f};
    floatx4 O[4] = {{0.f, 0.f, 0.f, 0.f},
                    {0.f, 0.f, 0.f, 0.f},
                    {0.f, 0.f, 0.f, 0.f},
                    {0.f, 0.f, 0.f, 0.f}};

    const float* rbbase = rbh + (size_t)(qs + (quad << 2)) * SEQ + lq;
    float rbv[16];
#pragma unroll
    for (int nt = 0; nt < 4; ++nt)
#pragma unroll
      for (int r = 0; r < 4; ++r)
        rbv[nt * 4 + r] = rbbase[(size_t)r * SEQ + (nt << 4)];

    for (int c = 0; c < nc; ++c) {
      const int t0 = c << 6;
      const bool diag = (c == nc - 1);
      float rbn[16];
      if (c + 1 < nc) {
        const float* rn = rbbase + t0 + 64;
#pragma unroll
        for (int nt = 0; nt < 4; ++nt)
#pragma unroll
          for (int r = 0; r < 4; ++r)
            rbn[nt * 4 + r] = rn[(size_t)r * SEQ + (nt << 4)];
      }

#pragma unroll
      for (int nt = 0; nt < 4; ++nt) {
        const int kr = t0 + (nt << 4) + lq;
        const unsigned char* kbase = (const unsigned char*)sK + (kr << 7);
        short8 bK0 = *(const short8*)(kbase + ((quad ^ (kr & 7)) << 4));
        short8 bK1 = *(const short8*)(kbase + (((quad + 4) ^ (kr & 7)) << 4));
        floatx4 s = {0.f, 0.f, 0.f, 0.f};
        s = __builtin_amdgcn_mfma_f32_16x16x32_bf16(aQ0, bK0, s, 0, 0, 0);
        s = __builtin_amdgcn_mfma_f32_16x16x32_bf16(aQ1, bK1, s, 0, 0, 0);
        if (diag) {
          const int col = t0 + (nt << 4) + lq;
#pragma unroll
          for (int r = 0; r < 4; ++r) {
            const int row = qs + (quad << 2) + r;
            float p = 0.f;
            if (col <= row) p = __expf(s[r] * 0.125f + rbv[nt * 4 + r]);
            lsum[r] += p;
            sPt[w][(quad << 2) + r][(nt << 4) + lq] = f2bf(p);
          }
        } else {
#pragma unroll
          for (int r = 0; r < 4; ++r) {
            const float p = __expf(s[r] * 0.125f + rbv[nt * 4 + r]);
            lsum[r] += p;
            sPt[w][(quad << 2) + r][(nt << 4) + lq] = f2bf(p);
          }
        }
      }

      short8 bV0[4], bV1[4];
#pragma unroll
      for (int nt = 0; nt < 4; ++nt) {
        const int vr = (nt << 4) + lq;
        const unsigned char* vbase = (const unsigned char*)sV + (vr << 10);
        const int cc = (t0 >> 3) + quad;
        bV0[nt] = *(const short8*)(vbase + ((cc ^ (vr & 7)) << 4));
        bV1[nt] = *(const short8*)(vbase + (((cc + 4) ^ (vr & 7)) << 4));
      }

      short8 aP0 = *(const short8*)&sPt[w][lq][quad << 3];
      short8 aP1 = *(const short8*)&sPt[w][lq][32 + (quad << 3)];

      {
        unsigned short* pgrow =
            Pg + (bh * SEQ + (qs + lq)) * SEQ + t0 + (quad << 3);
        *(short8*)pgrow = aP0;
        *(short8*)(pgrow + 32) = aP1;
      }

#pragma unroll
      for (int nt = 0; nt < 4; ++nt) {
        O[nt] = __builtin_amdgcn_mfma_f32_16x16x32_bf16(aP0, bV0[nt], O[nt], 0,
                                                        0, 0);
        O[nt] = __builtin_amdgcn_mfma_f32_16x16x32_bf16(aP1, bV1[nt], O[nt], 0,
                                                        0, 0);
      }

      if (c + 1 < nc) {
#pragma unroll
        for (int i = 0; i < 16; ++i) rbv[i] = rbn[i];
      }
    }

#pragma unroll
    for (int off = 1; off < 16; off <<= 1)
#pragma unroll
      for (int r = 0; r < 4; ++r) lsum[r] += __shfl_xor(lsum[r], off);
    float invl[4];
#pragma unroll
    for (int r = 0; r < 4; ++r) invl[r] = 1.f / lsum[r];
    if (lq == 0) {
#pragma unroll
      for (int r = 0; r < 4; ++r)
        flWS[bh * SEQ + qs + (quad << 2) + r] = invl[r] * 0.0625f;
    }
#pragma unroll
    for (int nt = 0; nt < 4; ++nt)
#pragma unroll
      for (int r = 0; r < 4; ++r) {
        const int row = qs + (quad << 2) + r;
        ctxb[((size_t)b * SEQ + row) * D_MODEL + h * D_K + (nt << 4) + lq] =
            f2bf(O[nt][r] * invl[r]);
      }
  }
}

// ---------------------------------------------------------------------------
// Head-mean reduce (unchanged).
// ---------------------------------------------------------------------------
__global__ __launch_bounds__(256) void attn_reduce(
    const unsigned short* __restrict__ Pg, const float* __restrict__ flWS,
    float* __restrict__ attn_mean) {
  const int b = blockIdx.x, rt = blockIdx.y, cs = blockIdx.z;
#pragma unroll
  for (int k = 0; k < 4; ++k) {
    const int slot = threadIdx.x + (k << 8);
    const int row = (rt << 6) + (slot >> 4);
    const int col0 = (cs << 7) + ((slot & 15) << 3);
    float acc[8] = {0.f, 0.f, 0.f, 0.f, 0.f, 0.f, 0.f, 0.f};
    if (col0 <= row) {
      for (int h = 0; h < NUM_HEADS; ++h) {
        const size_t base = (((size_t)b * NUM_HEADS + h) << 9) + row;
        const float f = flWS[base];
        const uint4 pk = *(const uint4*)&Pg[(base << 9) + col0];
        acc[0] += bf2f((unsigned short)(pk.x & 0xffff)) * f;
        acc[1] += bf2f((unsigned short)(pk.x >> 16)) * f;
        acc[2] += bf2f((unsigned short)(pk.y & 0xffff)) * f;
        acc[3] += bf2f((unsigned short)(pk.y >> 16)) * f;
        acc[4] += bf2f((unsigned short)(pk.z & 0xffff)) * f;
        acc[5] += bf2f((unsigned short)(pk.z >> 16)) * f;
        acc[6] += bf2f((unsigned short)(pk.w & 0xffff)) * f;
        acc[7] += bf2f((unsigned short)(pk.w >> 16)) * f;
      }
    }
    float4 o0, o1;
    o0.x = (col0 + 0 <= row) ? acc[0] : 0.f;
    o0.y = (col0 + 1 <= row) ? acc[1] : 0.f;
    o0.z = (col0 + 2 <= row) ? acc[2] : 0.f;
    o0.w = (col0 + 3 <= row) ? acc[3] : 0.f;
    o1.x = (col0 + 4 <= row) ? acc[4] : 0.f;
    o1.y = (col0 + 5 <= row) ? acc[5] : 0.f;
    o1.z = (col0 + 6 <= row) ? acc[6] : 0.f;
    o1.w = (col0 + 7 <= row) ? acc[7] : 0.f;
    float* dst = attn_mean + (((size_t)b << 9) + row) * SEQ + col0;
    *(float4*)dst = o0;
    *(float4*)(dst + 4) = o1;
  }
}

// ---------------------------------------------------------------------------
extern "C" void kernel_launch(void* const* d_in, const int* in_sizes, int n_in,
                              void* d_out, int out_size, void* d_ws,
                              size_t ws_size, hipStream_t stream) {
  const float* query = (const float*)d_in[0];
  const float* key_ = (const float*)d_in[1];
  const float* value = (const float*)d_in[2];
  const float* wq_w = (const float*)d_in[3];
  const float* wq_b = (const float*)d_in[4];
  const float* wk_w = (const float*)d_in[5];
  const float* wk_b = (const float*)d_in[6];
  const float* wv_w = (const float*)d_in[7];
  const float* wv_b = (const float*)d_in[8];
  const float* wo_w = (const float*)d_in[9];
  const float* wo_b = (const float*)d_in[10];
  const float* rel_bias = (const float*)d_in[11];

  float* out = (float*)d_out;                              // [B,S,1024]
  float* attn_mean = out + (size_t)BATCH * SEQ * D_MODEL;  // [B,S,512]

  const size_t ME = (size_t)BATCH * SEQ * D_MODEL;    // 8.4M elems
  const size_t WE = (size_t)D_MODEL * D_MODEL;        // 1M elems
  const size_t RE = (size_t)BATCH * NUM_HEADS * SEQ;  // 131072 rows

  unsigned short* Qb = (unsigned short*)d_ws;  // Qb | Kb contiguous
  unsigned short* Kb = Qb + ME;
  unsigned short* Vt = Kb + ME;
  unsigned short* ctxb = Vt + ME;
  unsigned short* wob = ctxb + ME;                    // 2 MB
  float* flWS = (float*)(wob + WE);                   // 0.5 MB
  unsigned short* Pg = (unsigned short*)(flWS + RE);  // 134 MB
  // transient buffers alias the Pg region (dead before attn writes Pg):
  unsigned short* xq = Pg;  // xq | xk | xv contiguous (ME each)
  unsigned short* xk = xq + ME;
  unsigned short* xv = xk + ME;
  unsigned short* wqb = xv + ME;  // wqb | wkb | wvb contiguous (WE each)
  unsigned short* wkb = wqb + WE;
  unsigned short* wvb = wkb + WE;

  conv_all<<<14336, 256, 0, stream>>>(query, key_, value, wq_w, wk_w, wv_w,
                                      wo_w, xq, xk, xv, wqb, wkb, wvb, wob);

  dim3 qkvg(8, 64, 3);  // N/128 x M/128 x {Q,K,V} (swizzled in-kernel)
  qkv_gemm<<<qkvg, 256, 0, stream>>>(xq, wqb, wq_b, wk_b, wv_b, Qb, Vt);

  dim3 agrid(BATCH, NUM_HEADS);  // one block per (b,h), K/V in LDS
  attn_mfma<<<agrid, 512, 0, stream>>>(Qb, Kb, Vt, rel_bias, ctxb, Pg, flWS);

  dim3 rgrid(BATCH, 8, 4);
  attn_reduce<<<rgrid, 256, 0, stream>>>(Pg, flWS, attn_mean);

  dim3 gblk(8, 64);
  out_gemm<<<gblk, 256, 0, stream>>>(ctxb, wob, wo_b, out);
}

// Round 9
// 303.697 us; speedup vs baseline: 1.1941x; 1.0165x over previous
//
#include <hip/hip_runtime.h>
#include <hip/hip_bf16.h>
#include <math.h>

#define D_MODEL 1024
#define NUM_HEADS 16
#define D_K 64
#define BATCH 16
#define SEQ 512

typedef __attribute__((ext_vector_type(8))) short short8;
typedef __attribute__((ext_vector_type(4))) float floatx4;

__device__ inline unsigned short f2bf(float f) {
  __hip_bfloat16 h = __float2bfloat16(f);
  return *reinterpret_cast<unsigned short*>(&h);
}
__device__ inline float bf2f(unsigned short us) {
  unsigned u = ((unsigned)us) << 16;
  return __uint_as_float(u);
}

typedef const __attribute__((address_space(1))) unsigned int glb_u32;
typedef __attribute__((address_space(3))) unsigned int lds_u32;

__device__ inline void load16_to_lds(const void* g, void* l) {
  __builtin_amdgcn_global_load_lds((glb_u32*)(uintptr_t)g,
                                   (lds_u32*)(unsigned int)(uintptr_t)l, 16, 0,
                                   0);
}

// ---------------------------------------------------------------------------
// Fused fp32 -> bf16 convert for all 7 tensors (one dispatch). (R5 verified)
// ---------------------------------------------------------------------------
__global__ __launch_bounds__(256) void conv_all(
    const float* __restrict__ q, const float* __restrict__ k,
    const float* __restrict__ v, const float* __restrict__ w0,
    const float* __restrict__ w1, const float* __restrict__ w2,
    const float* __restrict__ w3, unsigned short* __restrict__ xq,
    unsigned short* __restrict__ xk, unsigned short* __restrict__ xv,
    unsigned short* __restrict__ d0, unsigned short* __restrict__ d1,
    unsigned short* __restrict__ d2, unsigned short* __restrict__ d3) {
  const size_t MG = 1048576, WG = 131072;
  const size_t g = (size_t)blockIdx.x * 256 + threadIdx.x;
  const float* src;
  unsigned short* dst;
  size_t idx;
  if (g < 3 * MG) {
    const int r = (int)(g >> 20);
    idx = g & (MG - 1);
    src = (r == 0) ? q : (r == 1) ? k : v;
    dst = (r == 0) ? xq : (r == 1) ? xk : xv;
  } else {
    const size_t gw = g - 3 * MG;
    const int r = (int)(gw >> 17);
    idx = gw & (WG - 1);
    src = (r == 0) ? w0 : (r == 1) ? w1 : (r == 2) ? w2 : w3;
    dst = (r == 0) ? d0 : (r == 1) ? d1 : (r == 2) ? d2 : d3;
  }
  const float4 a = ((const float4*)src)[2 * idx];
  const float4 b = ((const float4*)src)[2 * idx + 1];
  short8 o;
  o[0] = f2bf(a.x); o[1] = f2bf(a.y); o[2] = f2bf(a.z); o[3] = f2bf(a.w);
  o[4] = f2bf(b.x); o[5] = f2bf(b.y); o[6] = f2bf(b.z); o[7] = f2bf(b.w);
  ((short8*)dst)[idx] = o;
}

// ---------------------------------------------------------------------------
// Fused QKV GEMM: XCD swizzle (T1) + double-buffered LDS prefetch (T3-min).
// R5/R8-verified: 59 µs, MfmaUtil 36% — the 2-barrier structure's optimum.
// ---------------------------------------------------------------------------
__global__ __launch_bounds__(256) void qkv_gemm(
    const unsigned short* __restrict__ Xall,  // xq | xk | xv (ME each)
    const unsigned short* __restrict__ Wall,  // wqb | wkb | wvb (WE each)
    const float* __restrict__ bq, const float* __restrict__ bk,
    const float* __restrict__ bv,
    unsigned short* __restrict__ QKout,  // Qb | Kb (ME each)
    unsigned short* __restrict__ Vt) {
  constexpr int K = 1024;
  const size_t ME = (size_t)BATCH * SEQ * D_MODEL;
  const size_t WE = (size_t)D_MODEL * D_MODEL;

  // ---- XCD-aware swizzle: grid (8,64,3) = 1536 blocks, 1536 % 8 == 0 ----
  const int f = blockIdx.x + (blockIdx.y << 3) + (blockIdx.z << 9);
  const int virt = ((f & 7) * 192) + (f >> 3);
  const int xi = virt & 7;     // N tile 0..7
  const int rest = virt >> 3;  // 0..191
  const int yi = rest & 63;    // M tile 0..63
  const int z = rest >> 6;     // 0..2 {Q,K,V}

  const unsigned short* A = Xall + (size_t)z * ME;
  const unsigned short* Bw = Wall + (size_t)z * WE;
  const float* bias = (z == 0) ? bq : (z == 1) ? bk : bv;

  __shared__ __align__(16) unsigned short sA[2][128 * 64];
  __shared__ __align__(16) unsigned short sB[2][128 * 64];
  const int tid = threadIdx.x;
  const int w = tid >> 6, lane = tid & 63;
  const int quad = lane >> 4, lq = lane & 15;
  const int wm = w >> 1, wn = w & 1;
  const int m0 = yi << 7, n0 = xi << 7;

  const int lrow8 = lane >> 3;
  const int sg = lane & 7;

  floatx4 acc[4][4];
#pragma unroll
  for (int i = 0; i < 4; ++i)
#pragma unroll
    for (int j = 0; j < 4; ++j) acc[i][j] = {0.f, 0.f, 0.f, 0.f};

  // stage K-tile kt into LDS buffer buf
  auto stage = [&](int buf, int kt) {
#pragma unroll
    for (int i = 0; i < 4; ++i) {
      const int row = (i << 5) + (w << 3) + lrow8;
      const int g = sg ^ (row & 7);
      const unsigned short* gA = A + (size_t)(m0 + row) * K + kt + (g << 3);
      const unsigned short* gB = Bw + (size_t)(n0 + row) * K + kt + (g << 3);
      load16_to_lds(gA, &sA[buf][((i << 5) + (w << 3)) * 64]);
      load16_to_lds(gB, &sB[buf][((i << 5) + (w << 3)) * 64]);
    }
  };

  stage(0, 0);
  __syncthreads();
  int cur = 0;
  for (int kt = 0; kt < K; kt += 64) {
    if (kt + 64 < K) stage(cur ^ 1, kt + 64);
#pragma unroll
    for (int s = 0; s < 2; ++s) {
      short8 aF[4], bF[4];
#pragma unroll
      for (int mi = 0; mi < 4; ++mi) {
        const int row = (wm << 6) + (mi << 4) + lq;
        const int g = ((s << 2) + quad) ^ (row & 7);
        aF[mi] = *(const short8*)&sA[cur][row * 64 + (g << 3)];
      }
#pragma unroll
      for (int ni = 0; ni < 4; ++ni) {
        const int row = (wn << 6) + (ni << 4) + lq;
        const int g = ((s << 2) + quad) ^ (row & 7);
        bF[ni] = *(const short8*)&sB[cur][row * 64 + (g << 3)];
      }
#pragma unroll
      for (int mi = 0; mi < 4; ++mi)
#pragma unroll
        for (int ni = 0; ni < 4; ++ni)
          acc[mi][ni] = __builtin_amdgcn_mfma_f32_16x16x32_bf16(
              aF[mi], bF[ni], acc[mi][ni], 0, 0, 0);
    }
    __syncthreads();
    cur ^= 1;
  }

#pragma unroll
  for (int ni = 0; ni < 4; ++ni) {
    const int n = n0 + (wn << 6) + (ni << 4) + lq;
    const float bn = bias[n];
    const int hh = n >> 6, dk = n & 63;
#pragma unroll
    for (int mi = 0; mi < 4; ++mi) {
      const int mb = m0 + (wm << 6) + (mi << 4) + (quad << 2);
      const int bb = mb >> 9, ss = mb & 511;
      if (z == 2) {
        ushort4 pk;
        pk.x = f2bf(acc[mi][ni][0] + bn);
        pk.y = f2bf(acc[mi][ni][1] + bn);
        pk.z = f2bf(acc[mi][ni][2] + bn);
        pk.w = f2bf(acc[mi][ni][3] + bn);
        *(ushort4*)&Vt[((size_t)(bb * NUM_HEADS + hh) * D_K + dk) * SEQ + ss] =
            pk;
      } else {
        unsigned short* dst = QKout + (size_t)z * ME;
#pragma unroll
        for (int r = 0; r < 4; ++r)
          dst[((size_t)(bb * NUM_HEADS + hh) * SEQ + ss + r) * D_K + dk] =
              f2bf(acc[mi][ni][r] + bn);
      }
    }
  }
}

// ---------------------------------------------------------------------------
// TAIL FUSED: out_gemm + attn_reduce in ONE dispatch, interleaved so each CU
// co-hosts one MFMA-bound out-block and one BW-bound reduce-block (separate
// pipes overlap; m114). Blocks 0-255,512-767 = out; 256-511,768-1023 = reduce.
// 64KB LDS -> 2 blocks/CU -> blocks c and c+256 (different types) co-resident.
// Bodies bit-identical to the R8-verified kernels.
// ---------------------------------------------------------------------------
__global__ __launch_bounds__(256) void tail_fused(
    const unsigned short* __restrict__ A,   // ctxb
    const unsigned short* __restrict__ Bw,  // wob
    const float* __restrict__ bias,         // wo_b
    float* __restrict__ Cout,               // out
    const unsigned short* __restrict__ Pg, const float* __restrict__ flWS,
    float* __restrict__ attn_mean) {
  __shared__ __align__(16) unsigned short sA[2][128 * 64];
  __shared__ __align__(16) unsigned short sB[2][128 * 64];
  const int bid = blockIdx.x;
  const int tid = threadIdx.x;

  if ((bid & 256) == 0) {
    // ---------------- out_gemm body ----------------
    constexpr int K = 1024;
    const int w = tid >> 6, lane = tid & 63;
    const int quad = lane >> 4, lq = lane & 15;
    const int wm = w >> 1, wn = w & 1;

    const int f = (bid >= 512) ? (bid - 256) : bid;  // 0..511, f%8 == bid%8
    const int virt = ((f & 7) << 6) + (f >> 3);
    const int m0 = (virt >> 3) << 7, n0 = (virt & 7) << 7;

    const int lrow8 = lane >> 3;
    const int sg = lane & 7;

    floatx4 acc[4][4];
#pragma unroll
    for (int i = 0; i < 4; ++i)
#pragma unroll
      for (int j = 0; j < 4; ++j) acc[i][j] = {0.f, 0.f, 0.f, 0.f};

    auto stage = [&](int buf, int kt) {
#pragma unroll
      for (int i = 0; i < 4; ++i) {
        const int row = (i << 5) + (w << 3) + lrow8;
        const int g = sg ^ (row & 7);
        const unsigned short* gA = A + (size_t)(m0 + row) * K + kt + (g << 3);
        const unsigned short* gB = Bw + (size_t)(n0 + row) * K + kt + (g << 3);
        load16_to_lds(gA, &sA[buf][((i << 5) + (w << 3)) * 64]);
        load16_to_lds(gB, &sB[buf][((i << 5) + (w << 3)) * 64]);
      }
    };

    stage(0, 0);
    __syncthreads();
    int cur = 0;
    for (int kt = 0; kt < K; kt += 64) {
      if (kt + 64 < K) stage(cur ^ 1, kt + 64);
#pragma unroll
      for (int s = 0; s < 2; ++s) {
        short8 aF[4], bF[4];
#pragma unroll
        for (int mi = 0; mi < 4; ++mi) {
          const int row = (wm << 6) + (mi << 4) + lq;
          const int g = ((s << 2) + quad) ^ (row & 7);
          aF[mi] = *(const short8*)&sA[cur][row * 64 + (g << 3)];
        }
#pragma unroll
        for (int ni = 0; ni < 4; ++ni) {
          const int row = (wn << 6) + (ni << 4) + lq;
          const int g = ((s << 2) + quad) ^ (row & 7);
          bF[ni] = *(const short8*)&sB[cur][row * 64 + (g << 3)];
        }
#pragma unroll
        for (int mi = 0; mi < 4; ++mi)
#pragma unroll
          for (int ni = 0; ni < 4; ++ni)
            acc[mi][ni] = __builtin_amdgcn_mfma_f32_16x16x32_bf16(
                aF[mi], bF[ni], acc[mi][ni], 0, 0, 0);
      }
      __syncthreads();
      cur ^= 1;
    }

#pragma unroll
    for (int ni = 0; ni < 4; ++ni) {
      const int n = n0 + (wn << 6) + (ni << 4) + lq;
      const float bn = bias[n];
#pragma unroll
      for (int mi = 0; mi < 4; ++mi) {
        const int mb = m0 + (wm << 6) + (mi << 4) + (quad << 2);
#pragma unroll
        for (int r = 0; r < 4; ++r)
          Cout[(size_t)(mb + r) * 1024 + n] = acc[mi][ni][r] + bn;
      }
    }
  } else {
    // ---------------- attn_reduce body ----------------
    const int rid = (bid >= 768) ? (bid - 512) : (bid - 256);  // 0..511
    const int b = rid >> 5, rt = (rid >> 2) & 7, cs = rid & 3;
#pragma unroll
    for (int k = 0; k < 4; ++k) {
      const int slot = tid + (k << 8);
      const int row = (rt << 6) + (slot >> 4);
      const int col0 = (cs << 7) + ((slot & 15) << 3);
      float acc[8] = {0.f, 0.f, 0.f, 0.f, 0.f, 0.f, 0.f, 0.f};
      if (col0 <= row) {
        for (int h = 0; h < NUM_HEADS; ++h) {
          const size_t base = (((size_t)b * NUM_HEADS + h) << 9) + row;
          const float ff = flWS[base];
          const uint4 pk = *(const uint4*)&Pg[(base << 9) + col0];
          acc[0] += bf2f((unsigned short)(pk.x & 0xffff)) * ff;
          acc[1] += bf2f((unsigned short)(pk.x >> 16)) * ff;
          acc[2] += bf2f((unsigned short)(pk.y & 0xffff)) * ff;
          acc[3] += bf2f((unsigned short)(pk.y >> 16)) * ff;
          acc[4] += bf2f((unsigned short)(pk.z & 0xffff)) * ff;
          acc[5] += bf2f((unsigned short)(pk.z >> 16)) * ff;
          acc[6] += bf2f((unsigned short)(pk.w & 0xffff)) * ff;
          acc[7] += bf2f((unsigned short)(pk.w >> 16)) * ff;
        }
      }
      float4 o0, o1;
      o0.x = (col0 + 0 <= row) ? acc[0] : 0.f;
      o0.y = (col0 + 1 <= row) ? acc[1] : 0.f;
      o0.z = (col0 + 2 <= row) ? acc[2] : 0.f;
      o0.w = (col0 + 3 <= row) ? acc[3] : 0.f;
      o1.x = (col0 + 4 <= row) ? acc[4] : 0.f;
      o1.y = (col0 + 5 <= row) ? acc[5] : 0.f;
      o1.z = (col0 + 6 <= row) ? acc[6] : 0.f;
      o1.w = (col0 + 7 <= row) ? acc[7] : 0.f;
      float* dst = attn_mean + (((size_t)b << 9) + row) * SEQ + col0;
      *(float4*)dst = o0;
      *(float4*)(dst + 4) = o1;
    }
  }
}

// ---------------------------------------------------------------------------
// Fixed-max MFMA attention, v4.1: K/V resident in LDS (R8 verified).
// ---------------------------------------------------------------------------
__global__ __launch_bounds__(512) void attn_mfma(
    const unsigned short* __restrict__ Qb,  // [B,H,S,64] bf16
    const unsigned short* __restrict__ Kb,  // [B,H,S,64] bf16
    const unsigned short* __restrict__ Vt,  // [B,H,64,S] bf16
    const float* __restrict__ rb,           // [H,512,512] fp32
    unsigned short* __restrict__ ctxb,      // [B,S,1024] bf16
    unsigned short* __restrict__ Pg,        // [B,H,S,S] bf16, unnorm exp(v)
    float* __restrict__ flWS) {             // [B,H,S]  1/(16 l)
  const int b = blockIdx.x;
  const int h = blockIdx.y;
  const int tid = threadIdx.x;
  const int w = tid >> 6, lane = tid & 63;
  const int quad = lane >> 4, lq = lane & 15;

  __shared__ __align__(16) unsigned short sK[512 * 64];   // 64 KB, rows 128B
  __shared__ __align__(16) unsigned short sV[64 * 512];   // 64 KB, rows 1KB
  __shared__ __align__(16) unsigned short sPt[8][16][72]; // 18 KB

  const size_t bh = (size_t)b * NUM_HEADS + h;
  const unsigned short* Qh = Qb + bh * SEQ * D_K;
  const unsigned short* Kh = Kb + bh * SEQ * D_K;
  const unsigned short* Vh = Vt + bh * D_K * SEQ;
  const float* rbh = rb + (size_t)h * SEQ * SEQ;

  // ---- stage K,V -> LDS; source pre-swizzled so swizzled reads are linear
#pragma unroll
  for (int it = 0; it < 8; ++it) {
    const int L = (it << 13) + (tid << 4);  // byte offset, 8KB/iter
    {
      const int rk = L >> 7, ck = (L >> 4) & 7;
      load16_to_lds(
          (const unsigned char*)Kh + (L & ~127) + ((ck ^ (rk & 7)) << 4),
          (unsigned char*)sK + L);
    }
    {
      const int rv = L >> 10, cv = (L >> 4) & 63;
      load16_to_lds(
          (const unsigned char*)Vh + (L & ~1023) + ((cv ^ (rv & 7)) << 4),
          (unsigned char*)sV + L);
    }
  }
  __syncthreads();

#pragma unroll 1
  for (int si = 0; si < 4; ++si) {
    const int st = (si == 0) ? w : (si == 1) ? (15 - w)
                 : (si == 2) ? (16 + w) : (31 - w);
    const int qs = st << 4;
    const int nc = (st >> 2) + 1;

    short8 aQ0, aQ1;
    {
      const unsigned short* qrow = Qh + (size_t)(qs + lq) * D_K + (quad << 3);
      aQ0 = *(const short8*)(qrow);
      aQ1 = *(const short8*)(qrow + 32);
    }

    float lsum[4] = {0.f, 0.f, 0.f, 0.f};
    floatx4 O[4] = {{0.f, 0.f, 0.f, 0.f},
                    {0.f, 0.f, 0.f, 0.f},
                    {0.f, 0.f, 0.f, 0.f},
                    {0.f, 0.f, 0.f, 0.f}};

    const float* rbbase = rbh + (size_t)(qs + (quad << 2)) * SEQ + lq;
    float rbv[16];
#pragma unroll
    for (int nt = 0; nt < 4; ++nt)
#pragma unroll
      for (int r = 0; r < 4; ++r)
        rbv[nt * 4 + r] = rbbase[(size_t)r * SEQ + (nt << 4)];

    for (int c = 0; c < nc; ++c) {
      const int t0 = c << 6;
      const bool diag = (c == nc - 1);
      float rbn[16];
      if (c + 1 < nc) {
        const float* rn = rbbase + t0 + 64;
#pragma unroll
        for (int nt = 0; nt < 4; ++nt)
#pragma unroll
          for (int r = 0; r < 4; ++r)
            rbn[nt * 4 + r] = rn[(size_t)r * SEQ + (nt << 4)];
      }

#pragma unroll
      for (int nt = 0; nt < 4; ++nt) {
        const int kr = t0 + (nt << 4) + lq;
        const unsigned char* kbase = (const unsigned char*)sK + (kr << 7);
        short8 bK0 = *(const short8*)(kbase + ((quad ^ (kr & 7)) << 4));
        short8 bK1 = *(const short8*)(kbase + (((quad + 4) ^ (kr & 7)) << 4));
        floatx4 s = {0.f, 0.f, 0.f, 0.f};
        s = __builtin_amdgcn_mfma_f32_16x16x32_bf16(aQ0, bK0, s, 0, 0, 0);
        s = __builtin_amdgcn_mfma_f32_16x16x32_bf16(aQ1, bK1, s, 0, 0, 0);
        if (diag) {
          const int col = t0 + (nt << 4) + lq;
#pragma unroll
          for (int r = 0; r < 4; ++r) {
            const int row = qs + (quad << 2) + r;
            float p = 0.f;
            if (col <= row) p = __expf(s[r] * 0.125f + rbv[nt * 4 + r]);
            lsum[r] += p;
            sPt[w][(quad << 2) + r][(nt << 4) + lq] = f2bf(p);
          }
        } else {
#pragma unroll
          for (int r = 0; r < 4; ++r) {
            const float p = __expf(s[r] * 0.125f + rbv[nt * 4 + r]);
            lsum[r] += p;
            sPt[w][(quad << 2) + r][(nt << 4) + lq] = f2bf(p);
          }
        }
      }

      short8 bV0[4], bV1[4];
#pragma unroll
      for (int nt = 0; nt < 4; ++nt) {
        const int vr = (nt << 4) + lq;
        const unsigned char* vbase = (const unsigned char*)sV + (vr << 10);
        const int cc = (t0 >> 3) + quad;
        bV0[nt] = *(const short8*)(vbase + ((cc ^ (vr & 7)) << 4));
        bV1[nt] = *(const short8*)(vbase + (((cc + 4) ^ (vr & 7)) << 4));
      }

      short8 aP0 = *(const short8*)&sPt[w][lq][quad << 3];
      short8 aP1 = *(const short8*)&sPt[w][lq][32 + (quad << 3)];

      {
        unsigned short* pgrow =
            Pg + (bh * SEQ + (qs + lq)) * SEQ + t0 + (quad << 3);
        *(short8*)pgrow = aP0;
        *(short8*)(pgrow + 32) = aP1;
      }

#pragma unroll
      for (int nt = 0; nt < 4; ++nt) {
        O[nt] = __builtin_amdgcn_mfma_f32_16x16x32_bf16(aP0, bV0[nt], O[nt], 0,
                                                        0, 0);
        O[nt] = __builtin_amdgcn_mfma_f32_16x16x32_bf16(aP1, bV1[nt], O[nt], 0,
                                                        0, 0);
      }

      if (c + 1 < nc) {
#pragma unroll
        for (int i = 0; i < 16; ++i) rbv[i] = rbn[i];
      }
    }

#pragma unroll
    for (int off = 1; off < 16; off <<= 1)
#pragma unroll
      for (int r = 0; r < 4; ++r) lsum[r] += __shfl_xor(lsum[r], off);
    float invl[4];
#pragma unroll
    for (int r = 0; r < 4; ++r) invl[r] = 1.f / lsum[r];
    if (lq == 0) {
#pragma unroll
      for (int r = 0; r < 4; ++r)
        flWS[bh * SEQ + qs + (quad << 2) + r] = invl[r] * 0.0625f;
    }
#pragma unroll
    for (int nt = 0; nt < 4; ++nt)
#pragma unroll
      for (int r = 0; r < 4; ++r) {
        const int row = qs + (quad << 2) + r;
        ctxb[((size_t)b * SEQ + row) * D_MODEL + h * D_K + (nt << 4) + lq] =
            f2bf(O[nt][r] * invl[r]);
      }
  }
}

// ---------------------------------------------------------------------------
extern "C" void kernel_launch(void* const* d_in, const int* in_sizes, int n_in,
                              void* d_out, int out_size, void* d_ws,
                              size_t ws_size, hipStream_t stream) {
  const float* query = (const float*)d_in[0];
  const float* key_ = (const float*)d_in[1];
  const float* value = (const float*)d_in[2];
  const float* wq_w = (const float*)d_in[3];
  const float* wq_b = (const float*)d_in[4];
  const float* wk_w = (const float*)d_in[5];
  const float* wk_b = (const float*)d_in[6];
  const float* wv_w = (const float*)d_in[7];
  const float* wv_b = (const float*)d_in[8];
  const float* wo_w = (const float*)d_in[9];
  const float* wo_b = (const float*)d_in[10];
  const float* rel_bias = (const float*)d_in[11];

  float* out = (float*)d_out;                              // [B,S,1024]
  float* attn_mean = out + (size_t)BATCH * SEQ * D_MODEL;  // [B,S,512]

  const size_t ME = (size_t)BATCH * SEQ * D_MODEL;    // 8.4M elems
  const size_t WE = (size_t)D_MODEL * D_MODEL;        // 1M elems
  const size_t RE = (size_t)BATCH * NUM_HEADS * SEQ;  // 131072 rows

  unsigned short* Qb = (unsigned short*)d_ws;  // Qb | Kb contiguous
  unsigned short* Kb = Qb + ME;
  unsigned short* Vt = Kb + ME;
  unsigned short* ctxb = Vt + ME;
  unsigned short* wob = ctxb + ME;                    // 2 MB
  float* flWS = (float*)(wob + WE);                   // 0.5 MB
  unsigned short* Pg = (unsigned short*)(flWS + RE);  // 134 MB
  // transient buffers alias the Pg region (dead before attn writes Pg):
  unsigned short* xq = Pg;  // xq | xk | xv contiguous (ME each)
  unsigned short* xk = xq + ME;
  unsigned short* xv = xk + ME;
  unsigned short* wqb = xv + ME;  // wqb | wkb | wvb contiguous (WE each)
  unsigned short* wkb = wqb + WE;
  unsigned short* wvb = wkb + WE;

  conv_all<<<14336, 256, 0, stream>>>(query, key_, value, wq_w, wk_w, wv_w,
                                      wo_w, xq, xk, xv, wqb, wkb, wvb, wob);

  dim3 qkvg(8, 64, 3);  // N/128 x M/128 x {Q,K,V} (swizzled in-kernel)
  qkv_gemm<<<qkvg, 256, 0, stream>>>(xq, wqb, wq_b, wk_b, wv_b, Qb, Vt);

  dim3 agrid(BATCH, NUM_HEADS);  // one block per (b,h), K/V in LDS
  attn_mfma<<<agrid, 512, 0, stream>>>(Qb, Kb, Vt, rel_bias, ctxb, Pg, flWS);

  // out_gemm + attn_reduce fused: 1024 blocks, type-interleaved per CU
  tail_fused<<<1024, 256, 0, stream>>>(ctxb, wob, wo_b, out, Pg, flWS,
                                       attn_mean);
}